// Round 12
// baseline (26199.179 us; speedup 1.0000x reference)
//
#include <hip/hip_runtime.h>

typedef unsigned short u16;
typedef unsigned int u32;
typedef unsigned long long u64;
typedef __attribute__((ext_vector_type(4))) float f32x4;
typedef __attribute__((ext_vector_type(8))) short bf16x8;
typedef __attribute__((ext_vector_type(4))) u16 u16x4;
typedef __attribute__((ext_vector_type(8))) u16 u16x8;
typedef __attribute__((ext_vector_type(4))) u32 u32x4;

#define AGENT_SCOPE __HIP_MEMORY_SCOPE_AGENT

__device__ __forceinline__ u64 lda64(const u64* p) {
  return __hip_atomic_load((u64*)p, __ATOMIC_RELAXED, AGENT_SCOPE);
}
__device__ __forceinline__ int loadai(const int* p) {
  return __hip_atomic_load((int*)p, __ATOMIC_RELAXED, AGENT_SCOPE);
}
__device__ __forceinline__ void sta32(u32* p, u32 v) {
  __hip_atomic_store(p, v, __ATOMIC_RELAXED, AGENT_SCOPE);
}

__device__ __forceinline__ u16 f2bf(float f) {
  u32 u = __builtin_bit_cast(u32, f);
  u = (u + 0x7FFFu + ((u >> 16) & 1u)) >> 16;
  return (u16)u;
}
__device__ __forceinline__ float b2f(u16 h) {
  return __builtin_bit_cast(float, ((u32)h) << 16);
}
__device__ __forceinline__ float sigf(float x) { return 1.0f / (1.0f + __expf(-x)); }
__device__ __forceinline__ float tanh_(float x) { return 2.0f / (1.0f + __expf(-2.0f * x)) - 1.0f; }

// ---------------------------------------------------------------------------
// fp32 -> bf16 elementwise (vectorized)
// ---------------------------------------------------------------------------
__global__ __launch_bounds__(256) void cvt_bf16_vec(
    const float* __restrict__ in, u16* __restrict__ out, int n4)
{
  int i = blockIdx.x * blockDim.x + threadIdx.x;
  const int stride = gridDim.x * blockDim.x;
  for (; i < n4; i += stride) {
    f32x4 v = ((const f32x4*)in)[i];
    u16x4 o;
    #pragma unroll
    for (int e = 0; e < 4; ++e) o[e] = f2bf(v[e]);
    ((u16x4*)out)[i] = o;
  }
}

// ---------------------------------------------------------------------------
// fp32 (R x C) -> bf16 transposed (C x R)
// ---------------------------------------------------------------------------
__global__ __launch_bounds__(256) void transpose_f32_bf16(
    const float* __restrict__ in, u16* __restrict__ out, int R, int C)
{
  __shared__ float t[32][33];
  const int tx = threadIdx.x & 31, ty = threadIdx.x >> 5; // ty in [0,8)
  const int bx = blockIdx.x * 32, by = blockIdx.y * 32;
  #pragma unroll
  for (int i = 0; i < 4; ++i)
    t[ty + i * 8][tx] = in[(long)(by + ty + i * 8) * C + bx + tx];
  __syncthreads();
  #pragma unroll
  for (int i = 0; i < 4; ++i)
    out[(long)(bx + ty + i * 8) * R + by + tx] = f2bf(t[tx][ty + i * 8]);
}

// ---------------------------------------------------------------------------
// bf16 GEMM: C[M x N] = A[M x K] @ Bt[N x K]^T + bias.
// ---------------------------------------------------------------------------
template <bool BF16_OUT>
__global__ __launch_bounds__(256, 2) void gemm_bt(
    const u16* __restrict__ A, const u16* __restrict__ Bt,
    const float* __restrict__ bias, void* __restrict__ Cv,
    int M, int N, int K)
{
  __shared__ u16 As[128 * 64];
  __shared__ u16 Bs[128 * 64];
  const int tid = threadIdx.x;
  const int lane = tid & 63;
  const int wv = tid >> 6;
  const int wm = wv >> 1, wn = wv & 1;
  const long row0 = (long)blockIdx.x * 128;
  const long col0 = (long)blockIdx.y * 128;
  const int lr8 = lane >> 3, lc8 = lane & 7;
  const int fr = lane & 15, fk = (lane >> 4) * 8;
  f32x4 acc[4][4] = {};

  for (int kt = 0; kt < K; kt += 64) {
    __syncthreads();
    #pragma unroll
    for (int ch = 0; ch < 4; ++ch) {
      const int r = wv * 32 + ch * 8;
      const u16* gA = A + (row0 + r + lr8) * (long)K + kt + lc8 * 8;
      __builtin_amdgcn_global_load_lds(
          (const __attribute__((address_space(1))) u32*)gA,
          (__attribute__((address_space(3))) u32*)&As[r * 64], 16, 0, 0);
      const u16* gB = Bt + (col0 + r + lr8) * (long)K + kt + lc8 * 8;
      __builtin_amdgcn_global_load_lds(
          (const __attribute__((address_space(1))) u32*)gB,
          (__attribute__((address_space(3))) u32*)&Bs[r * 64], 16, 0, 0);
    }
    __syncthreads();
    #pragma unroll
    for (int kk = 0; kk < 2; ++kk) {
      bf16x8 af[4], bfv[4];
      #pragma unroll
      for (int m = 0; m < 4; ++m)
        af[m] = *(const bf16x8*)&As[(wm * 64 + m * 16 + fr) * 64 + kk * 32 + fk];
      #pragma unroll
      for (int n = 0; n < 4; ++n)
        bfv[n] = *(const bf16x8*)&Bs[(wn * 64 + n * 16 + fr) * 64 + kk * 32 + fk];
      #pragma unroll
      for (int m = 0; m < 4; ++m)
        #pragma unroll
        for (int n = 0; n < 4; ++n)
          acc[m][n] = __builtin_amdgcn_mfma_f32_16x16x32_bf16(af[m], bfv[n], acc[m][n], 0, 0, 0);
    }
  }

  const int orow = (lane >> 4) * 4, ocol = lane & 15;
  #pragma unroll
  for (int m = 0; m < 4; ++m) {
    #pragma unroll
    for (int n = 0; n < 4; ++n) {
      const long cb = col0 + wn * 64 + n * 16 + ocol;
      const float bv = bias[cb];
      #pragma unroll
      for (int r = 0; r < 4; ++r) {
        const long rr = row0 + wm * 64 + m * 16 + orow + r;
        const float v = acc[m][n][r] + bv;
        if (BF16_OUT) ((u16*)Cv)[rr * (long)N + cb] = f2bf(v);
        else          ((float*)Cv)[rr * (long)N + cb] = v;
      }
    }
  }
}

// ---------------------------------------------------------------------------
// Persistent cooperative scan — paired wave specialization, 512 threads:
// waves 0-3 = COMPUTE (one batch each; r8 broadcast-A MFMA; Who in VGPR,
// Whl in LDS frag-order; ZERO global loads in loop); waves 4-7 = COMM
// (one batch each: poll global tags via 3-level sticky ladder, stage to
// LDS, set scalar per-batch flag). Per-batch flags => no cross-batch
// coupling inside the WG (r11's mistake). Transport r6/r9-proven.
// ---------------------------------------------------------------------------
#define SS 2048
#define FAROFF 16384   // words; far slice offset inside each tag buffer

__device__ __forceinline__ bool ge4(u32x4 v, u32 t) {
  return ((v[0] >> 16) >= t) & ((v[1] >> 16) >= t) &
         ((v[2] >> 16) >= t) & ((v[3] >> 16) >= t);
}
__device__ __forceinline__ bool ge2(u64 w, u32 t) {
  return ((((u32)(w >> 16)) & 0xffffu) >= t) & (((u32)(w >> 48)) >= t);
}

__device__ __forceinline__ void ld8_sc0(const u32* p, u32x4& a, u32x4& b) {
  asm volatile("global_load_dwordx4 %0, %2, off sc0\n\t"
               "global_load_dwordx4 %1, %3, off sc0\n\t"
               "s_waitcnt vmcnt(0)"
               : "=&v"(a), "=&v"(b) : "v"(p), "v"(p + 4));
}
__device__ __forceinline__ void ld8_sc1(const u32* p, u32x4& a, u32x4& b) {
  asm volatile("global_load_dwordx4 %0, %2, off sc1\n\t"
               "global_load_dwordx4 %1, %3, off sc1\n\t"
               "s_waitcnt vmcnt(0)"
               : "=&v"(a), "=&v"(b) : "v"(p), "v"(p + 4));
}

__device__ __forceinline__ void pollfar(const u32* pf, u32 tag, u32x4& a, u32x4& b) {
  const u64* q = (const u64*)pf;
  u64 w0 = lda64(q), w1 = lda64(q + 1), w2 = lda64(q + 2), w3 = lda64(q + 3);
  int tries = 0;
  while (!(ge2(w0, tag) & ge2(w1, tag) & ge2(w2, tag) & ge2(w3, tag))) {
    if (++tries > 2) __builtin_amdgcn_s_sleep(1);
    w0 = lda64(q); w1 = lda64(q + 1); w2 = lda64(q + 2); w3 = lda64(q + 3);
  }
  a[0] = (u32)w0; a[1] = (u32)(w0 >> 32); a[2] = (u32)w1; a[3] = (u32)(w1 >> 32);
  b[0] = (u32)w2; b[1] = (u32)(w2 >> 32); b[2] = (u32)w3; b[3] = (u32)(w3 >> 32);
}

__device__ __forceinline__ void poll8(const u32* pn, u32 tag, int lvl, int* lvlsh,
                                      u32x4& a, u32x4& b) {
  if (lvl == 0) {
    int tries = 0;
    for (;;) {
      ld8_sc0(pn, a, b);
      if (ge4(a, tag) && ge4(b, tag)) return;
      if (++tries > 8000) { *lvlsh = 1; lvl = 1; break; }  // sticky escalate
      if (tries > 32) __builtin_amdgcn_s_sleep(1);
    }
  }
  if (lvl == 1) {
    int tries = 0;
    for (;;) {
      ld8_sc1(pn, a, b);
      if (ge4(a, tag) && ge4(b, tag)) return;
      if (++tries > 8000) { *lvlsh = 2; break; }           // sticky escalate
      if (tries > 32) __builtin_amdgcn_s_sleep(1);
    }
  }
  pollfar(pn + FAROFF, tag, a, b);
}

// producer: far copy always (agent atomic); near copy sc1 store
__device__ __forceinline__ void stdual(u32* pn, u32 word, bool far_grp) {
  sta32(pn + FAROFF, word);
  if (!far_grp)
    asm volatile("global_store_dword %0, %1, off sc1" :: "v"(pn), "v"(word) : "memory");
}

// compute-wave spin on ONE LDS epoch flag (per-batch, no cross-coupling)
__device__ __forceinline__ void spin1(const int* f, int target) {
  const volatile int* vf = (const volatile int*)f;
  int iters = 0;
  while (*vf < target) {
    if (++iters > 64) __builtin_amdgcn_s_sleep(1);
  }
  __atomic_signal_fence(__ATOMIC_ACQUIRE);
}

__global__ __launch_bounds__(512, 1) void scan_kernel(
    const u16* __restrict__ XZL, const float* __restrict__ XZO,
    const float* __restrict__ TS,
    const u16* __restrict__ WhlT, const u16* __restrict__ WhoT,
    u32* Ht, u32* HMt, u32* Ut,
    u16* __restrict__ HS,
    float* __restrict__ out_h, float* __restrict__ out_c,
    int* chk)
{
  const int tid = threadIdx.x;
  const int lane = tid & 63;
  const int wv = tid >> 6;           // 0-3 compute(batch wv); 4-7 comm(batch wv-4)

  __shared__ u16 whl_l[4][16][512];  // [gate][ks][lane*8] frag-ordered, 64 KB
  __shared__ u16 stg_h[4 * 528];
  __shared__ u16 stg_m[4 * 528];
  __shared__ u16 stg_u[4 * 528];
  __shared__ float in_zb[2][4][16][4];  // [buf][batch][j][gate]
  __shared__ float in_zo[2][4][16];
  __shared__ float in_t[2][4];
  __shared__ int flag_h[4], flag_m[4], flag_u[4];
  __shared__ u16 xcl[256];
  __shared__ int lvl_sh;

  // ---- XCD discovery ----
  if (tid == 0) {
    u32 xcc;
    asm volatile("s_getreg_b32 %0, hwreg(HW_REG_XCC_ID)" : "=s"(xcc));
    sta32((u32*)&chk[blockIdx.x], (xcc & 7u) + 1u);
    lvl_sh = 0;
  }
  if (tid < 4) { flag_h[tid] = 0; flag_m[tid] = 0; flag_u[tid] = 0; }
  if (tid < 256) {
    int v;
    do { v = loadai(&chk[tid]); } while (v == 0);
    xcl[tid] = (u16)(v - 1);
  }
  __syncthreads();

  // ---- group formation (identical in every thread) ----
  int g, w;
  bool far_grp;
  {
    int cnt[8] = {0, 0, 0, 0, 0, 0, 0, 0};
    const int my = (int)xcl[blockIdx.x];
    int rank = 0;
    for (int bi = 0; bi < 256; ++bi) {
      const int e = (int)xcl[bi];
      ++cnt[e];
      rank += (e == my && bi < (int)blockIdx.x) ? 1 : 0;
    }
    bool ok = true;
    #pragma unroll
    for (int e = 0; e < 8; ++e) ok = ok && (cnt[e] == 32);
    if (ok) { g = my; w = rank; far_grp = false; }
    else    { g = (int)(blockIdx.x & 7); w = (int)(blockIdx.x >> 3); far_grp = true; }
  }
  const int j0 = w * 16;

  // ---- stage Whl into LDS frag-order (comm waves, one gate each) ----
  if (wv >= 4) {
    const int gt = wv - 4;
    #pragma unroll
    for (int ks = 0; ks < 16; ++ks)
      *(u16x8*)&whl_l[gt][ks][lane * 8] =
        *(const u16x8*)&WhlT[(size_t)(gt * 512 + j0 + (lane & 15)) * 512 + ks * 32 + (lane >> 4) * 8];
  }
  __syncthreads();

  u32* const Hg  = Ht  + g * 2048;
  u32* const HMg = HMt + g * 2048;
  u32* const Ug  = Ut  + g * 2048;

  if (wv < 4) {
    // ================= COMPUTE WAVE (batch b = g*4+wv) =================
    const int b = wv;
    const int fr = lane & 15, kc8 = (lane >> 4) * 8;
    const int hi = lane >> 4;
    bf16x8 who_r[16];                 // 64 VGPRs — fits, no spill
    #pragma unroll
    for (int ks = 0; ks < 16; ++ks)
      who_r[ks] = *(const bf16x8*)&WhoT[(size_t)(j0 + fr) * 512 + ks * 32 + kc8];
    asm volatile("s_waitcnt vmcnt(0)" ::: "memory");   // drain before loop

    float c_r = 0.0f;
    u32* const HMb = HMg + b * 512;
    u32* const Ub  = Ug  + b * 512;
    u32* const Hb  = Hg  + b * 512;

    for (int s = 0; s < SS; ++s) {
      const u32 tagv = (u32)(s + 1);
      const int buf = s & 1;

      // ---- phase 1: z = h @ Whl (broadcast-A, 4 gate chains) ----
      spin1(&flag_h[b], s + 1);
      f32x4 az0 = {}, az1 = {}, az2 = {}, az3 = {};
      #pragma unroll
      for (int ks = 0; ks < 16; ++ks) {
        bf16x8 af = *(const bf16x8*)&stg_h[b * 528 + ks * 32 + kc8];
        az0 = __builtin_amdgcn_mfma_f32_16x16x32_bf16(af, *(const bf16x8*)&whl_l[0][ks][lane * 8], az0, 0, 0, 0);
        az1 = __builtin_amdgcn_mfma_f32_16x16x32_bf16(af, *(const bf16x8*)&whl_l[1][ks][lane * 8], az1, 0, 0, 0);
        az2 = __builtin_amdgcn_mfma_f32_16x16x32_bf16(af, *(const bf16x8*)&whl_l[2][ks][lane * 8], az2, 0, 0, 0);
        az3 = __builtin_amdgcn_mfma_f32_16x16x32_bf16(af, *(const bf16x8*)&whl_l[3][ks][lane * 8], az3, 0, 0, 0);
      }
      // broadcast rows identical; col = fr
      const float zi = az0[0] + in_zb[buf][b][fr][0];
      const float zf = az1[0] + in_zb[buf][b][fr][1];
      const float zg = az2[0] + in_zb[buf][b][fr][2];
      const float zo = az3[0] + in_zb[buf][b][fr][3];
      const float zot = in_zo[buf][b][fr];
      const float tt  = in_t[buf][b];
      const float cn = sigf(zf) * c_r + sigf(zi) * tanh_(zg);
      const float hm = sigf(zo) * tanh_(cn);
      c_r = cn;
      if (hi == 0) stdual(&HMb[j0 + fr], (tagv << 16) | (u32)f2bf(hm), far_grp);

      // ---- phase 2: k1 (split 8+8 chains) ----
      spin1(&flag_m[b], s + 1);
      f32x4 aka = {}, akb = {};
      #pragma unroll
      for (int ks = 0; ks < 8; ++ks) {
        bf16x8 afa = *(const bf16x8*)&stg_m[b * 528 + ks * 32 + kc8];
        bf16x8 afb = *(const bf16x8*)&stg_m[b * 528 + (ks + 8) * 32 + kc8];
        aka = __builtin_amdgcn_mfma_f32_16x16x32_bf16(afa, who_r[ks], aka, 0, 0, 0);
        akb = __builtin_amdgcn_mfma_f32_16x16x32_bf16(afb, who_r[ks + 8], akb, 0, 0, 0);
      }
      const float k1 = tanh_(zot + aka[0] + akb[0]);
      const float uu = hm + tt * k1;
      if (hi == 0) stdual(&Ub[j0 + fr], (tagv << 16) | (u32)f2bf(uu), far_grp);

      // ---- phase 3: k2, h_new (split 8+8) ----
      spin1(&flag_u[b], s + 1);
      f32x4 a2a = {}, a2b = {};
      #pragma unroll
      for (int ks = 0; ks < 8; ++ks) {
        bf16x8 afa = *(const bf16x8*)&stg_u[b * 528 + ks * 32 + kc8];
        bf16x8 afb = *(const bf16x8*)&stg_u[b * 528 + (ks + 8) * 32 + kc8];
        a2a = __builtin_amdgcn_mfma_f32_16x16x32_bf16(afa, who_r[ks], a2a, 0, 0, 0);
        a2b = __builtin_amdgcn_mfma_f32_16x16x32_bf16(afb, who_r[ks + 8], a2b, 0, 0, 0);
      }
      const float k2 = tanh_(zot + a2a[0] + a2b[0]);
      const float hn = hm + 0.5f * tt * (k1 + k2);
      if (hi == 0) {
        stdual(&Hb[j0 + fr], (tagv << 16) | (u32)f2bf(hn), far_grp);
        HS[((size_t)(g * 4 + b) * SS + s) * 512 + j0 + fr] = f2bf(hn);
        if (s == SS - 1) out_h[(size_t)(g * 4 + b) * 512 + j0 + fr] = hn;
      }
    }
    if (hi == 0) out_c[(size_t)(g * 4 + b) * 512 + j0 + fr] = c_r;
  } else {
    // ================= COMM WAVE (batch cw = wv-4) =================
    const int cw = wv - 4;
    const int b = g * 4 + cw;
    u32* const Pm = HMg + cw * 512;
    u32* const Pu = Ug  + cw * 512;
    u32* const Ph = Hg  + cw * 512;

    // prologue: zero h stage, stage inputs(0), flag
    {
      u16x8 z8 = {0, 0, 0, 0, 0, 0, 0, 0};
      *(u16x8*)&stg_h[cw * 528 + lane * 8] = z8;
      if (lane < 16) {
        const u16* p = XZL + ((size_t)b * SS + 0) * 2048 + j0 + lane;
        f32x4 z; z[0] = b2f(p[0]); z[1] = b2f(p[512]);
        z[2] = b2f(p[1024]); z[3] = b2f(p[1536]);
        *(f32x4*)&in_zb[0][cw][lane][0] = z;
        in_zo[0][cw][lane] = XZO[((size_t)b * SS + 0) * 512 + j0 + lane];
        if (lane == 0) in_t[0][cw] = TS[(size_t)b * SS + 0];
      }
      asm volatile("s_waitcnt vmcnt(0) lgkmcnt(0)" ::: "memory");
      if (lane == 0) *(volatile int*)&flag_h[cw] = 1;
    }

    u32x4 pa, pb;
    for (int s = 0; s < SS; ++s) {
      const u32 tagv = (u32)(s + 1);
      // stage inputs(s+1) — drains inside this wave's polls, off compute path
      if (s + 1 < SS && lane < 16) {
        const int nb = (s + 1) & 1;
        const u16* p = XZL + ((size_t)b * SS + s + 1) * 2048 + j0 + lane;
        f32x4 z; z[0] = b2f(p[0]); z[1] = b2f(p[512]);
        z[2] = b2f(p[1024]); z[3] = b2f(p[1536]);
        *(f32x4*)&in_zb[nb][cw][lane][0] = z;
        in_zo[nb][cw][lane] = XZO[((size_t)b * SS + s + 1) * 512 + j0 + lane];
        if (lane == 0) in_t[nb][cw] = TS[(size_t)b * SS + s + 1];
      }

      // poll hm
      int lvl = far_grp ? 2 : *(volatile int*)&lvl_sh;
      poll8(Pm + lane * 8, tagv, lvl, &lvl_sh, pa, pb);
      {
        u16x8 hv;
        #pragma unroll
        for (int i = 0; i < 4; ++i) {
          hv[i] = (u16)(pa[i] & 0xffffu);
          hv[4 + i] = (u16)(pb[i] & 0xffffu);
        }
        *(u16x8*)&stg_m[cw * 528 + lane * 8] = hv;
      }
      asm volatile("s_waitcnt lgkmcnt(0)" ::: "memory");
      if (lane == 0) *(volatile int*)&flag_m[cw] = s + 1;

      // poll u
      lvl = far_grp ? 2 : *(volatile int*)&lvl_sh;
      poll8(Pu + lane * 8, tagv, lvl, &lvl_sh, pa, pb);
      {
        u16x8 hv;
        #pragma unroll
        for (int i = 0; i < 4; ++i) {
          hv[i] = (u16)(pa[i] & 0xffffu);
          hv[4 + i] = (u16)(pb[i] & 0xffffu);
        }
        *(u16x8*)&stg_u[cw * 528 + lane * 8] = hv;
      }
      asm volatile("s_waitcnt lgkmcnt(0)" ::: "memory");
      if (lane == 0) *(volatile int*)&flag_u[cw] = s + 1;

      // poll h (for next step)
      if (s + 1 < SS) {
        lvl = far_grp ? 2 : *(volatile int*)&lvl_sh;
        poll8(Ph + lane * 8, tagv, lvl, &lvl_sh, pa, pb);
        {
          u16x8 hv;
          #pragma unroll
          for (int i = 0; i < 4; ++i) {
            hv[i] = (u16)(pa[i] & 0xffffu);
            hv[4 + i] = (u16)(pb[i] & 0xffffu);
          }
          *(u16x8*)&stg_h[cw * 528 + lane * 8] = hv;
        }
        asm volatile("s_waitcnt lgkmcnt(0)" ::: "memory");
        if (lane == 0) *(volatile int*)&flag_h[cw] = s + 2;
      }
    }
  }
}

// ---------------------------------------------------------------------------
// Host launch
// ---------------------------------------------------------------------------
extern "C" void kernel_launch(void* const* d_in, const int* in_sizes, int n_in,
                              void* d_out, int out_size, void* d_ws, size_t ws_size,
                              hipStream_t stream)
{
  const long B = 32, S = 2048, O = 512;
  const long MS = B * S; // 65536 rows

  const float* x   = (const float*)d_in[0];
  const float* ts  = (const float*)d_in[1];
  const float* Wxl = (const float*)d_in[2];
  const float* Whl = (const float*)d_in[3];
  const float* bl  = (const float*)d_in[4];
  const float* Wxo = (const float*)d_in[5];
  const float* Who = (const float*)d_in[6];
  const float* bo  = (const float*)d_in[7];
  const float* Wfc = (const float*)d_in[8];
  const float* bfc = (const float*)d_in[9];

  float* out = (float*)d_out;
  float* out_h = out + MS * O;
  float* out_c = out_h + B * 512;

  char* ws = (char*)d_ws;
  size_t off = 0;
  auto alloc = [&](size_t bytes) -> void* {
    void* p = ws + off;
    off += (bytes + 255) & ~(size_t)255;
    return p;
  };
  u16*   XZL  = (u16*)  alloc(MS * 2048 * 2);     // 268 MB, bf16
  u16*   xb   = (u16*)  alloc(MS * 512 * 2);      // 67 MB; HS aliases this
  u16*   HS   = xb;
  u16*   WxlT = (u16*)  alloc(2048 * 512 * 2);
  u16*   WhlT = (u16*)  alloc(2048 * 512 * 2);
  u16*   WxoT = (u16*)  alloc(512 * 512 * 2);
  u16*   WhoT = (u16*)  alloc(512 * 512 * 2);
  u16*   WfcT = (u16*)  alloc(512 * 512 * 2);
  u32*   Ht   = (u32*)  alloc(2 * 8 * 2048 * 4);  // near slice + far slice
  u32*   HMt  = (u32*)  alloc(2 * 8 * 2048 * 4);
  u32*   Ut   = (u32*)  alloc(2 * 8 * 2048 * 4);
  int*   chk  = (int*)  alloc(1024);

  float* XZO = out;   // (B,S,H) fp32 scratch in d_out; overwritten by final GEMM

  if (off > ws_size) return;

  // Reset tag/check buffers every launch (graph-replay stale tags).
  hipMemsetAsync(Ht, 0, 2 * 8 * 2048 * 4, stream);
  hipMemsetAsync(HMt, 0, 2 * 8 * 2048 * 4, stream);
  hipMemsetAsync(Ut, 0, 2 * 8 * 2048 * 4, stream);
  hipMemsetAsync(chk, 0, 1024, stream);

  cvt_bf16_vec<<<2048, 256, 0, stream>>>(x, xb, (int)(MS * 512 / 4));
  transpose_f32_bf16<<<dim3(64, 16), 256, 0, stream>>>(Wxl, WxlT, 512, 2048);
  transpose_f32_bf16<<<dim3(64, 16), 256, 0, stream>>>(Whl, WhlT, 512, 2048);
  transpose_f32_bf16<<<dim3(16, 16), 256, 0, stream>>>(Wxo, WxoT, 512, 512);
  transpose_f32_bf16<<<dim3(16, 16), 256, 0, stream>>>(Who, WhoT, 512, 512);
  transpose_f32_bf16<<<dim3(16, 16), 256, 0, stream>>>(Wfc, WfcT, 512, 512);

  gemm_bt<true ><<<dim3(512, 16), 256, 0, stream>>>(xb, WxlT, bl, XZL, (int)MS, 2048, 512);
  gemm_bt<false><<<dim3(512, 4), 256, 0, stream>>>(xb, WxoT, bo, XZO, (int)MS, 512, 512);

  {
    void* args[] = { (void*)&XZL, (void*)&XZO, (void*)&ts, (void*)&WhlT, (void*)&WhoT,
                     (void*)&Ht, (void*)&HMt, (void*)&Ut, (void*)&HS,
                     (void*)&out_h, (void*)&out_c, (void*)&chk };
    hipLaunchCooperativeKernel((void*)scan_kernel, dim3(256), dim3(512), args, 0, stream);
  }

  gemm_bt<false><<<dim3(512, 4), 256, 0, stream>>>(HS, WfcT, bfc, out, (int)MS, 512, 512);
}

// Round 13
// 11756.294 us; speedup vs baseline: 2.2285x; 2.2285x over previous
//
#include <hip/hip_runtime.h>

typedef unsigned short u16;
typedef unsigned int u32;
typedef unsigned long long u64;
typedef __attribute__((ext_vector_type(4))) float f32x4;
typedef __attribute__((ext_vector_type(8))) short bf16x8;
typedef __attribute__((ext_vector_type(4))) u16 u16x4;
typedef __attribute__((ext_vector_type(8))) u16 u16x8;
typedef __attribute__((ext_vector_type(4))) u32 u32x4;

#define AGENT_SCOPE __HIP_MEMORY_SCOPE_AGENT

__device__ __forceinline__ u64 lda64(const u64* p) {
  return __hip_atomic_load((u64*)p, __ATOMIC_RELAXED, AGENT_SCOPE);
}
__device__ __forceinline__ int loadai(const int* p) {
  return __hip_atomic_load((int*)p, __ATOMIC_RELAXED, AGENT_SCOPE);
}
__device__ __forceinline__ void sta32(u32* p, u32 v) {
  __hip_atomic_store(p, v, __ATOMIC_RELAXED, AGENT_SCOPE);
}

__device__ __forceinline__ u16 f2bf(float f) {
  u32 u = __builtin_bit_cast(u32, f);
  u = (u + 0x7FFFu + ((u >> 16) & 1u)) >> 16;
  return (u16)u;
}
__device__ __forceinline__ float b2f(u16 h) {
  return __builtin_bit_cast(float, ((u32)h) << 16);
}
__device__ __forceinline__ float sigf(float x) { return 1.0f / (1.0f + __expf(-x)); }
__device__ __forceinline__ float tanh_(float x) { return 2.0f / (1.0f + __expf(-2.0f * x)) - 1.0f; }

// ---------------------------------------------------------------------------
// fp32 -> bf16 elementwise (vectorized)
// ---------------------------------------------------------------------------
__global__ __launch_bounds__(256) void cvt_bf16_vec(
    const float* __restrict__ in, u16* __restrict__ out, int n4)
{
  int i = blockIdx.x * blockDim.x + threadIdx.x;
  const int stride = gridDim.x * blockDim.x;
  for (; i < n4; i += stride) {
    f32x4 v = ((const f32x4*)in)[i];
    u16x4 o;
    #pragma unroll
    for (int e = 0; e < 4; ++e) o[e] = f2bf(v[e]);
    ((u16x4*)out)[i] = o;
  }
}

// ---------------------------------------------------------------------------
// fp32 (R x C) -> bf16 transposed (C x R)
// ---------------------------------------------------------------------------
__global__ __launch_bounds__(256) void transpose_f32_bf16(
    const float* __restrict__ in, u16* __restrict__ out, int R, int C)
{
  __shared__ float t[32][33];
  const int tx = threadIdx.x & 31, ty = threadIdx.x >> 5; // ty in [0,8)
  const int bx = blockIdx.x * 32, by = blockIdx.y * 32;
  #pragma unroll
  for (int i = 0; i < 4; ++i)
    t[ty + i * 8][tx] = in[(long)(by + ty + i * 8) * C + bx + tx];
  __syncthreads();
  #pragma unroll
  for (int i = 0; i < 4; ++i)
    out[(long)(bx + ty + i * 8) * R + by + tx] = f2bf(t[tx][ty + i * 8]);
}

// ---------------------------------------------------------------------------
// bf16 GEMM: C[M x N] = A[M x K] @ Bt[N x K]^T + bias.
// ---------------------------------------------------------------------------
template <bool BF16_OUT>
__global__ __launch_bounds__(256, 2) void gemm_bt(
    const u16* __restrict__ A, const u16* __restrict__ Bt,
    const float* __restrict__ bias, void* __restrict__ Cv,
    int M, int N, int K)
{
  __shared__ u16 As[128 * 64];
  __shared__ u16 Bs[128 * 64];
  const int tid = threadIdx.x;
  const int lane = tid & 63;
  const int wv = tid >> 6;
  const int wm = wv >> 1, wn = wv & 1;
  const long row0 = (long)blockIdx.x * 128;
  const long col0 = (long)blockIdx.y * 128;
  const int lr8 = lane >> 3, lc8 = lane & 7;
  const int fr = lane & 15, fk = (lane >> 4) * 8;
  f32x4 acc[4][4] = {};

  for (int kt = 0; kt < K; kt += 64) {
    __syncthreads();
    #pragma unroll
    for (int ch = 0; ch < 4; ++ch) {
      const int r = wv * 32 + ch * 8;
      const u16* gA = A + (row0 + r + lr8) * (long)K + kt + lc8 * 8;
      __builtin_amdgcn_global_load_lds(
          (const __attribute__((address_space(1))) u32*)gA,
          (__attribute__((address_space(3))) u32*)&As[r * 64], 16, 0, 0);
      const u16* gB = Bt + (col0 + r + lr8) * (long)K + kt + lc8 * 8;
      __builtin_amdgcn_global_load_lds(
          (const __attribute__((address_space(1))) u32*)gB,
          (__attribute__((address_space(3))) u32*)&Bs[r * 64], 16, 0, 0);
    }
    __syncthreads();
    #pragma unroll
    for (int kk = 0; kk < 2; ++kk) {
      bf16x8 af[4], bfv[4];
      #pragma unroll
      for (int m = 0; m < 4; ++m)
        af[m] = *(const bf16x8*)&As[(wm * 64 + m * 16 + fr) * 64 + kk * 32 + fk];
      #pragma unroll
      for (int n = 0; n < 4; ++n)
        bfv[n] = *(const bf16x8*)&Bs[(wn * 64 + n * 16 + fr) * 64 + kk * 32 + fk];
      #pragma unroll
      for (int m = 0; m < 4; ++m)
        #pragma unroll
        for (int n = 0; n < 4; ++n)
          acc[m][n] = __builtin_amdgcn_mfma_f32_16x16x32_bf16(af[m], bfv[n], acc[m][n], 0, 0, 0);
    }
  }

  const int orow = (lane >> 4) * 4, ocol = lane & 15;
  #pragma unroll
  for (int m = 0; m < 4; ++m) {
    #pragma unroll
    for (int n = 0; n < 4; ++n) {
      const long cb = col0 + wn * 64 + n * 16 + ocol;
      const float bv = bias[cb];
      #pragma unroll
      for (int r = 0; r < 4; ++r) {
        const long rr = row0 + wm * 64 + m * 16 + orow + r;
        const float v = acc[m][n][r] + bv;
        if (BF16_OUT) ((u16*)Cv)[rr * (long)N + cb] = f2bf(v);
        else          ((float*)Cv)[rr * (long)N + cb] = v;
      }
    }
  }
}

// ---------------------------------------------------------------------------
// Persistent cooperative scan — r9 wave-per-batch structure (best measured),
// plus issue-order surgery: (1) input prefetch issued right after phase-2
// poll (drains under compute, not in a poll's vmcnt window); (2) far-store
// DEFERRAL — insurance far copy held in a register, flushed after the next
// poll succeeds (pre-flushed before the poll only when escalated to far
// level; deadlock-free since near stores are always immediate); (3) HS /
// out_h stores deferred one phase boundary; (4) MFMA chains split 8+8.
// Transport unchanged: sc1 near store; consumer 3-level sticky ladder
// (sc0/L2 -> sc1/IF$ -> agent far slice). Hang impossible.
// ---------------------------------------------------------------------------
#define SS 2048
#define FAROFF 16384   // words; far slice offset inside each tag buffer

__device__ __forceinline__ bool ge4(u32x4 v, u32 t) {
  return ((v[0] >> 16) >= t) & ((v[1] >> 16) >= t) &
         ((v[2] >> 16) >= t) & ((v[3] >> 16) >= t);
}
__device__ __forceinline__ bool ge2(u64 w, u32 t) {
  return ((((u32)(w >> 16)) & 0xffffu) >= t) & (((u32)(w >> 48)) >= t);
}

__device__ __forceinline__ void ld8_sc0(const u32* p, u32x4& a, u32x4& b) {
  asm volatile("global_load_dwordx4 %0, %2, off sc0\n\t"
               "global_load_dwordx4 %1, %3, off sc0\n\t"
               "s_waitcnt vmcnt(0)"
               : "=&v"(a), "=&v"(b) : "v"(p), "v"(p + 4));
}
__device__ __forceinline__ void ld8_sc1(const u32* p, u32x4& a, u32x4& b) {
  asm volatile("global_load_dwordx4 %0, %2, off sc1\n\t"
               "global_load_dwordx4 %1, %3, off sc1\n\t"
               "s_waitcnt vmcnt(0)"
               : "=&v"(a), "=&v"(b) : "v"(p), "v"(p + 4));
}

__device__ __forceinline__ void pollfar(const u32* pf, u32 tag, u32x4& a, u32x4& b) {
  const u64* q = (const u64*)pf;
  u64 w0 = lda64(q), w1 = lda64(q + 1), w2 = lda64(q + 2), w3 = lda64(q + 3);
  int tries = 0;
  while (!(ge2(w0, tag) & ge2(w1, tag) & ge2(w2, tag) & ge2(w3, tag))) {
    if (++tries > 2) __builtin_amdgcn_s_sleep(1);
    w0 = lda64(q); w1 = lda64(q + 1); w2 = lda64(q + 2); w3 = lda64(q + 3);
  }
  a[0] = (u32)w0; a[1] = (u32)(w0 >> 32); a[2] = (u32)w1; a[3] = (u32)(w1 >> 32);
  b[0] = (u32)w2; b[1] = (u32)(w2 >> 32); b[2] = (u32)w3; b[3] = (u32)(w3 >> 32);
}

__device__ __forceinline__ void poll8(const u32* pn, u32 tag, int lvl, int* lvlsh,
                                      u32x4& a, u32x4& b) {
  if (lvl == 0) {
    int tries = 0;
    for (;;) {
      ld8_sc0(pn, a, b);
      if (ge4(a, tag) && ge4(b, tag)) return;
      if (++tries > 8000) { *lvlsh = 1; lvl = 1; break; }  // sticky escalate
      if (tries > 32) __builtin_amdgcn_s_sleep(1);
    }
  }
  if (lvl == 1) {
    int tries = 0;
    for (;;) {
      ld8_sc1(pn, a, b);
      if (ge4(a, tag) && ge4(b, tag)) return;
      if (++tries > 8000) { *lvlsh = 2; break; }           // sticky escalate
      if (tries > 32) __builtin_amdgcn_s_sleep(1);
    }
  }
  pollfar(pn + FAROFF, tag, a, b);
}

__global__ __launch_bounds__(256, 1) void scan_kernel(
    const u16* __restrict__ XZL, const float* __restrict__ XZO,
    const float* __restrict__ TS,
    const u16* __restrict__ WhlT, const u16* __restrict__ WhoT,
    u32* Ht, u32* HMt, u32* Ut,
    u16* __restrict__ HS,
    float* __restrict__ out_h, float* __restrict__ out_c,
    int* chk)
{
  const int tid = threadIdx.x;
  const int lane = tid & 63;
  const int wv = tid >> 6;
  const int fr = lane & 15;       // column index within the WG's 16 cols
  const int hi = lane >> 4;       // k-chunk / redundant-copy index

  __shared__ u16 whl_l[4][16][512];  // [gate][ks][lane*8] frag-ordered, 64 KB
  __shared__ u16 who_l[16][512];     // [ks][lane*8] frag-ordered, 16 KB
  __shared__ u16 stage_l[4][512];    // per-WAVE staging (h / hm / u), 4 KB
  __shared__ u16 xcl[256];
  __shared__ int lvl_sh;             // sticky escalation level (0/1/2)

  // ---- XCD discovery: publish own XCC_ID, gather all 256 ----
  if (tid == 0) {
    u32 xcc;
    asm volatile("s_getreg_b32 %0, hwreg(HW_REG_XCC_ID)" : "=s"(xcc));
    sta32((u32*)&chk[blockIdx.x], (xcc & 7u) + 1u);
    lvl_sh = 0;
  }
  {
    int v;
    do { v = loadai(&chk[tid]); } while (v == 0);
    xcl[tid] = (u16)(v - 1);
  }
  __syncthreads();

  // ---- group formation (identical computation in every WG) ----
  int g, w;
  bool far_grp;
  {
    int cnt[8] = {0, 0, 0, 0, 0, 0, 0, 0};
    const int my = (int)xcl[blockIdx.x];
    int rank = 0;
    for (int bi = 0; bi < 256; ++bi) {
      const int e = (int)xcl[bi];
      ++cnt[e];
      rank += (e == my && bi < (int)blockIdx.x) ? 1 : 0;
    }
    bool ok = true;
    #pragma unroll
    for (int e = 0; e < 8; ++e) ok = ok && (cnt[e] == 32);
    if (ok) { g = my; w = rank; far_grp = false; }
    else    { g = (int)(blockIdx.x & 7); w = (int)(blockIdx.x >> 3); far_grp = true; }
  }
  const int j0 = w * 16;
  const int b = g * 4 + wv;          // this wave's batch

  // ---- stage weights into LDS, fragment order (one-time) ----
  {
    const int g4 = wv;               // wave wv stages gate wv
    #pragma unroll
    for (int ks = 0; ks < 16; ++ks)
      *(u16x8*)&whl_l[g4][ks][lane * 8] =
        *(const u16x8*)&WhlT[(size_t)(g4 * 512 + j0 + fr) * 512 + ks * 32 + (lane >> 4) * 8];
    for (int ks = wv; ks < 16; ks += 4)
      *(u16x8*)&who_l[ks][lane * 8] =
        *(const u16x8*)&WhoT[(size_t)(j0 + fr) * 512 + ks * 32 + (lane >> 4) * 8];
  }
  __syncthreads();                   // the ONLY barrier before the loop

  const int kc8 = hi * 8;
  u32* const Hb  = Ht  + g * 2048 + wv * 512;
  u32* const HMb = HMt + g * 2048 + wv * 512;
  u32* const Ub  = Ut  + g * 2048 + wv * 512;

  // ---- prologue input prefetch (s = 0), per lane col = j0+fr ----
  float zb_c[4], zo_c, t_c;
  {
    const u16* p = XZL + ((size_t)b * SS + 0) * 2048 + j0 + fr;
    zb_c[0] = b2f(p[0]); zb_c[1] = b2f(p[512]);
    zb_c[2] = b2f(p[1024]); zb_c[3] = b2f(p[1536]);
    zo_c = XZO[((size_t)b * SS + 0) * 512 + j0 + fr];
    t_c  = TS[(size_t)b * SS + 0];
  }

  float c_r = 0.0f;                  // LSTM cell state, register-resident
  u32x4 pa, pb;
  u32* pend_p = nullptr;             // deferred far store (insurance copy)
  u32  pend_w = 0;
  float hn_pend = 0.0f;              // deferred HS value

  for (int s = 0; s < SS; ++s) {
    const u32 tagv = (u32)(s + 1);
    int lvl = far_grp ? 2 : *(volatile int*)&lvl_sh;

    // ---- phase 1: poll h(own batch), stage to wave-private LDS ----
    if (s == 0) {
      u16x8 z8 = {0, 0, 0, 0, 0, 0, 0, 0};
      *(u16x8*)&stage_l[wv][lane * 8] = z8;
    } else {
      if (hi == 0 && lvl >= 2 && pend_p) { sta32(pend_p, pend_w); pend_p = nullptr; }
      poll8(Hb + lane * 8, (u32)s, lvl, &lvl_sh, pa, pb);
      u16x8 hv;
      #pragma unroll
      for (int i = 0; i < 4; ++i) {
        hv[i] = (u16)(pa[i] & 0xffffu);
        hv[4 + i] = (u16)(pb[i] & 0xffffu);
      }
      *(u16x8*)&stage_l[wv][lane * 8] = hv;
      if (hi == 0) {
        if (pend_p) { sta32(pend_p, pend_w); pend_p = nullptr; }  // flush far(h)
        HS[((size_t)b * SS + (s - 1)) * 512 + j0 + fr] = f2bf(hn_pend);
      }
    }
    // (no barrier: per-wave DS queue is in-order; reads below see the writes)

    // ---- z = h @ Whl : 4 gate chains, split 8+8 (broadcast-A) ----
    f32x4 az0a = {}, az0b = {}, az1a = {}, az1b = {};
    f32x4 az2a = {}, az2b = {}, az3a = {}, az3b = {};
    #pragma unroll
    for (int ks = 0; ks < 8; ++ks) {
      bf16x8 afa = *(const bf16x8*)&stage_l[wv][ks * 32 + kc8];
      bf16x8 afb = *(const bf16x8*)&stage_l[wv][(ks + 8) * 32 + kc8];
      az0a = __builtin_amdgcn_mfma_f32_16x16x32_bf16(afa, *(const bf16x8*)&whl_l[0][ks][lane * 8], az0a, 0, 0, 0);
      az0b = __builtin_amdgcn_mfma_f32_16x16x32_bf16(afb, *(const bf16x8*)&whl_l[0][ks + 8][lane * 8], az0b, 0, 0, 0);
      az1a = __builtin_amdgcn_mfma_f32_16x16x32_bf16(afa, *(const bf16x8*)&whl_l[1][ks][lane * 8], az1a, 0, 0, 0);
      az1b = __builtin_amdgcn_mfma_f32_16x16x32_bf16(afb, *(const bf16x8*)&whl_l[1][ks + 8][lane * 8], az1b, 0, 0, 0);
      az2a = __builtin_amdgcn_mfma_f32_16x16x32_bf16(afa, *(const bf16x8*)&whl_l[2][ks][lane * 8], az2a, 0, 0, 0);
      az2b = __builtin_amdgcn_mfma_f32_16x16x32_bf16(afb, *(const bf16x8*)&whl_l[2][ks + 8][lane * 8], az2b, 0, 0, 0);
      az3a = __builtin_amdgcn_mfma_f32_16x16x32_bf16(afa, *(const bf16x8*)&whl_l[3][ks][lane * 8], az3a, 0, 0, 0);
      az3b = __builtin_amdgcn_mfma_f32_16x16x32_bf16(afb, *(const bf16x8*)&whl_l[3][ks + 8][lane * 8], az3b, 0, 0, 0);
    }

    // ---- gates (all 64 lanes; 4 redundant copies across hi) ----
    const float zi = az0a[0] + az0b[0] + zb_c[0];
    const float zf = az1a[0] + az1b[0] + zb_c[1];
    const float zg = az2a[0] + az2b[0] + zb_c[2];
    const float zo = az3a[0] + az3b[0] + zb_c[3];
    const float cn = sigf(zf) * c_r + sigf(zi) * tanh_(zg);
    const float hm = sigf(zo) * tanh_(cn);
    c_r = cn;
    if (hi == 0) {
      const u32 wd = (tagv << 16) | (u32)f2bf(hm);
      if (!far_grp)
        asm volatile("global_store_dword %0, %1, off sc1" :: "v"(&HMb[j0 + fr]), "v"(wd) : "memory");
      pend_p = &HMb[j0 + fr] + FAROFF; pend_w = wd;   // defer far copy
    }

    // ---- phase 2: poll hm ----
    lvl = far_grp ? 2 : *(volatile int*)&lvl_sh;
    if (hi == 0 && lvl >= 2 && pend_p) { sta32(pend_p, pend_w); pend_p = nullptr; }
    poll8(HMb + lane * 8, tagv, lvl, &lvl_sh, pa, pb);

    // issue next-step input prefetch NOW (drains under phase-2/3 compute)
    const int sn = (s + 1 < SS) ? s + 1 : s;
    float zb_n[4], zo_n, t_n;
    {
      const u16* p = XZL + ((size_t)b * SS + sn) * 2048 + j0 + fr;
      zb_n[0] = b2f(p[0]); zb_n[1] = b2f(p[512]);
      zb_n[2] = b2f(p[1024]); zb_n[3] = b2f(p[1536]);
      zo_n = XZO[((size_t)b * SS + sn) * 512 + j0 + fr];
      t_n  = TS[(size_t)b * SS + sn];
    }
    if (hi == 0 && pend_p) { sta32(pend_p, pend_w); pend_p = nullptr; }  // flush far(hm)
    {
      u16x8 hv;
      #pragma unroll
      for (int i = 0; i < 4; ++i) {
        hv[i] = (u16)(pa[i] & 0xffffu);
        hv[4 + i] = (u16)(pb[i] & 0xffffu);
      }
      *(u16x8*)&stage_l[wv][lane * 8] = hv;
    }
    f32x4 aka = {}, akb = {};
    #pragma unroll
    for (int ks = 0; ks < 8; ++ks) {
      bf16x8 afa = *(const bf16x8*)&stage_l[wv][ks * 32 + kc8];
      bf16x8 afb = *(const bf16x8*)&stage_l[wv][(ks + 8) * 32 + kc8];
      aka = __builtin_amdgcn_mfma_f32_16x16x32_bf16(afa, *(const bf16x8*)&who_l[ks][lane * 8], aka, 0, 0, 0);
      akb = __builtin_amdgcn_mfma_f32_16x16x32_bf16(afb, *(const bf16x8*)&who_l[ks + 8][lane * 8], akb, 0, 0, 0);
    }
    const float k1 = tanh_(zo_c + aka[0] + akb[0]);
    const float uu = hm + t_c * k1;
    if (hi == 0) {
      const u32 wd = (tagv << 16) | (u32)f2bf(uu);
      if (!far_grp)
        asm volatile("global_store_dword %0, %1, off sc1" :: "v"(&Ub[j0 + fr]), "v"(wd) : "memory");
      pend_p = &Ub[j0 + fr] + FAROFF; pend_w = wd;
    }

    // ---- phase 3: poll u ----
    lvl = far_grp ? 2 : *(volatile int*)&lvl_sh;
    if (hi == 0 && lvl >= 2 && pend_p) { sta32(pend_p, pend_w); pend_p = nullptr; }
    poll8(Ub + lane * 8, tagv, lvl, &lvl_sh, pa, pb);
    if (hi == 0 && pend_p) { sta32(pend_p, pend_w); pend_p = nullptr; }  // flush far(u)
    {
      u16x8 hv;
      #pragma unroll
      for (int i = 0; i < 4; ++i) {
        hv[i] = (u16)(pa[i] & 0xffffu);
        hv[4 + i] = (u16)(pb[i] & 0xffffu);
      }
      *(u16x8*)&stage_l[wv][lane * 8] = hv;
    }
    f32x4 a2a = {}, a2b = {};
    #pragma unroll
    for (int ks = 0; ks < 8; ++ks) {
      bf16x8 afa = *(const bf16x8*)&stage_l[wv][ks * 32 + kc8];
      bf16x8 afb = *(const bf16x8*)&stage_l[wv][(ks + 8) * 32 + kc8];
      a2a = __builtin_amdgcn_mfma_f32_16x16x32_bf16(afa, *(const bf16x8*)&who_l[ks][lane * 8], a2a, 0, 0, 0);
      a2b = __builtin_amdgcn_mfma_f32_16x16x32_bf16(afb, *(const bf16x8*)&who_l[ks + 8][lane * 8], a2b, 0, 0, 0);
    }
    const float k2 = tanh_(zo_c + a2a[0] + a2b[0]);
    const float hn = hm + 0.5f * t_c * (k1 + k2);
    if (hi == 0) {
      const u32 wd = (tagv << 16) | (u32)f2bf(hn);
      if (!far_grp)
        asm volatile("global_store_dword %0, %1, off sc1" :: "v"(&Hb[j0 + fr]), "v"(wd) : "memory");
      pend_p = &Hb[j0 + fr] + FAROFF; pend_w = wd;
      hn_pend = hn;                  // HS store deferred to next phase-1
    }

    #pragma unroll
    for (int i = 0; i < 4; ++i) zb_c[i] = zb_n[i];
    zo_c = zo_n; t_c = t_n;
  }

  if (hi == 0) {
    if (pend_p) sta32(pend_p, pend_w);
    HS[((size_t)b * SS + (SS - 1)) * 512 + j0 + fr] = f2bf(hn_pend);
    out_h[(size_t)b * 512 + j0 + fr] = hn_pend;
    out_c[(size_t)b * 512 + j0 + fr] = c_r;
  }
}

// ---------------------------------------------------------------------------
// Host launch
// ---------------------------------------------------------------------------
extern "C" void kernel_launch(void* const* d_in, const int* in_sizes, int n_in,
                              void* d_out, int out_size, void* d_ws, size_t ws_size,
                              hipStream_t stream)
{
  const long B = 32, S = 2048, O = 512;
  const long MS = B * S; // 65536 rows

  const float* x   = (const float*)d_in[0];
  const float* ts  = (const float*)d_in[1];
  const float* Wxl = (const float*)d_in[2];
  const float* Whl = (const float*)d_in[3];
  const float* bl  = (const float*)d_in[4];
  const float* Wxo = (const float*)d_in[5];
  const float* Who = (const float*)d_in[6];
  const float* bo  = (const float*)d_in[7];
  const float* Wfc = (const float*)d_in[8];
  const float* bfc = (const float*)d_in[9];

  float* out = (float*)d_out;
  float* out_h = out + MS * O;
  float* out_c = out_h + B * 512;

  char* ws = (char*)d_ws;
  size_t off = 0;
  auto alloc = [&](size_t bytes) -> void* {
    void* p = ws + off;
    off += (bytes + 255) & ~(size_t)255;
    return p;
  };
  u16*   XZL  = (u16*)  alloc(MS * 2048 * 2);     // 268 MB, bf16
  u16*   xb   = (u16*)  alloc(MS * 512 * 2);      // 67 MB; HS aliases this
  u16*   HS   = xb;
  u16*   WxlT = (u16*)  alloc(2048 * 512 * 2);
  u16*   WhlT = (u16*)  alloc(2048 * 512 * 2);
  u16*   WxoT = (u16*)  alloc(512 * 512 * 2);
  u16*   WhoT = (u16*)  alloc(512 * 512 * 2);
  u16*   WfcT = (u16*)  alloc(512 * 512 * 2);
  u32*   Ht   = (u32*)  alloc(2 * 8 * 2048 * 4);  // near slice + far slice
  u32*   HMt  = (u32*)  alloc(2 * 8 * 2048 * 4);
  u32*   Ut   = (u32*)  alloc(2 * 8 * 2048 * 4);
  int*   chk  = (int*)  alloc(1024);

  float* XZO = out;   // (B,S,H) fp32 scratch in d_out; overwritten by final GEMM

  if (off > ws_size) return;

  // Reset tag/check buffers every launch (graph-replay stale tags).
  hipMemsetAsync(Ht, 0, 2 * 8 * 2048 * 4, stream);
  hipMemsetAsync(HMt, 0, 2 * 8 * 2048 * 4, stream);
  hipMemsetAsync(Ut, 0, 2 * 8 * 2048 * 4, stream);
  hipMemsetAsync(chk, 0, 1024, stream);

  cvt_bf16_vec<<<2048, 256, 0, stream>>>(x, xb, (int)(MS * 512 / 4));
  transpose_f32_bf16<<<dim3(64, 16), 256, 0, stream>>>(Wxl, WxlT, 512, 2048);
  transpose_f32_bf16<<<dim3(64, 16), 256, 0, stream>>>(Whl, WhlT, 512, 2048);
  transpose_f32_bf16<<<dim3(16, 16), 256, 0, stream>>>(Wxo, WxoT, 512, 512);
  transpose_f32_bf16<<<dim3(16, 16), 256, 0, stream>>>(Who, WhoT, 512, 512);
  transpose_f32_bf16<<<dim3(16, 16), 256, 0, stream>>>(Wfc, WfcT, 512, 512);

  gemm_bt<true ><<<dim3(512, 16), 256, 0, stream>>>(xb, WxlT, bl, XZL, (int)MS, 2048, 512);
  gemm_bt<false><<<dim3(512, 4), 256, 0, stream>>>(xb, WxoT, bo, XZO, (int)MS, 512, 512);

  {
    void* args[] = { (void*)&XZL, (void*)&XZO, (void*)&ts, (void*)&WhlT, (void*)&WhoT,
                     (void*)&Ht, (void*)&HMt, (void*)&Ut, (void*)&HS,
                     (void*)&out_h, (void*)&out_c, (void*)&chk };
    hipLaunchCooperativeKernel((void*)scan_kernel, dim3(256), dim3(256), args, 0, stream);
  }

  gemm_bt<false><<<dim3(512, 4), 256, 0, stream>>>(HS, WfcT, bfc, out, (int)MS, 512, 512);
}